// Round 14
// baseline (83.095 us; speedup 1.0000x reference)
//
#include <hip/hip_runtime.h>
#include <hip/hip_bf16.h>
#include <math.h>

#define Bb 512
#define Tt 256
#define Cc 384
#define Hh 64

#define KP   72    // k_lds stride (shorts)
#define WPAD 72    // W buffer stride (shorts)
#define VTP  264   // V^T stride (shorts)
#define QBP  72    // q_lds stride (shorts)
#define PST  40    // P tile stride (shorts)
#define WCH  12288 // chunk-major W: 192*64 shorts per k-chunk

// LDS layout (shorts), R12-identical (117,760 B; 1 block/CU):
#define OFF_K  0
#define OFF_VT (256 * KP)                  // 18432
#define OFF_Q  (OFF_VT + 64 * VTP)         // 35328
#define OFF_P  (OFF_Q + 256 * QBP)         // 53760
#define LDST   (OFF_P + 8 * 16 * PST)      // 58880 shorts = 117,760 B
#define OFF_W0 0
#define OFF_W1 (192 * WPAD)                // 13824 (ends 27648 < 35328)

typedef __attribute__((ext_vector_type(8))) short short8;
typedef __attribute__((ext_vector_type(4))) short short4_;
typedef __attribute__((ext_vector_type(4))) float float4_;

static __device__ __forceinline__ unsigned short f2bf(float f) {
  __hip_bfloat16 h = __float2bfloat16(f);
  return *reinterpret_cast<unsigned short*>(&h);
}

// ---------------- kernel 0: pack W chunk-major bf16: wt[ks][192][64] ----------------
__global__ __launch_bounds__(256) void wtrans_kernel(
    const float* __restrict__ wq, const float* __restrict__ wk,
    const float* __restrict__ wv, unsigned short* __restrict__ wt) {
  __shared__ float tl[384 * 8];
  const int blk = blockIdx.x;
  const int wsel = blk >> 3, n0 = (blk & 7) * 8;
  const float* w = (wsel == 0) ? wq : (wsel == 1) ? wk : wv;
  const int t = threadIdx.x;
#pragma unroll
  for (int i = 0; i < 3; i++) {
    int id = i * 256 + t;
    int row = id >> 1, sg = id & 1;
    float4_ v = *(const float4_*)(w + row * Hh + n0 + sg * 4);
    *(float4_*)(&tl[row * 8 + sg * 4]) = v;
  }
  __syncthreads();
#pragma unroll
  for (int i = 0; i < 12; i++) {
    int id = i * 256 + t;
    int n = id / 384, k = id % 384;
    int row = wsel * 64 + n0 + n;
    wt[(size_t)(k >> 6) * WCH + row * 64 + (k & 63)] = f2bf(tl[k * 8 + n]);
  }
}

// ---------------- fused kernel: 2 batches/block; R12 phases + cross-batch x prefetch ----------------
// Phase A (R12): 8x1 wave grid, x GLOBAL->REG direct, W LDS dbuf, ONE lgkm
// barrier per chunk. Phase B: scatter Q/K/V. Before phase C of batch 0: issue
// batch 1's x-chunk-0 loads (32 regs held across C; C set ~90 + 32 = 122 <=
// the 128-VGPR cap of 512-thread blocks). Phase C: swapped-operand flash attn.
__global__ __launch_bounds__(512, 1) void fused_kernel(
    const float* __restrict__ x, const unsigned short* __restrict__ wt,
    float* __restrict__ out) {
  __shared__ unsigned short lds[LDST];
  unsigned short* k_lds  = lds + OFF_K;
  unsigned short* vt_lds = lds + OFF_VT;
  unsigned short* q_lds  = lds + OFF_Q;

  const int t = threadIdx.x;
  const int wid = t >> 6, lane = t & 63;
  const int fr = lane & 15, fg = lane >> 4;
  const float SC  = 0.05103103630798288f;   // 384^-0.5
  const float L2E = 1.4426950408889634f;

  float4_ nx[2][2][2];
  // preload batch 0, chunk 0
  {
    const float* xw0 = x + ((size_t)(blockIdx.x * 2) * Tt + wid * 32 + fr) * Cc + fg * 8;
#pragma unroll
    for (int mi = 0; mi < 2; mi++)
#pragma unroll
      for (int kk = 0; kk < 2; kk++)
#pragma unroll
        for (int h = 0; h < 2; h++)
          nx[mi][kk][h] = *(const float4_*)(xw0 + mi * 16 * Cc + kk * 32 + h * 4);
  }

#pragma unroll 1
  for (int bi = 0; bi < 2; bi++) {
    const int b = blockIdx.x * 2 + bi;
    const float* xw = x + ((size_t)b * Tt + wid * 32 + fr) * Cc + fg * 8;

    // ================= phase A: QKV = x[b] @ W =================
    float4_ acc[2][12];
#pragma unroll
    for (int i = 0; i < 2; i++)
#pragma unroll
      for (int j = 0; j < 12; j++) acc[i][j] = (float4_)0.f;

    short8 wv[3];
#pragma unroll
    for (int i = 0; i < 3; i++) {
      int id = t + i * 512;
      wv[i] = *(const short8*)(wt + (id >> 3) * 64 + (id & 7) * 8);
    }

#pragma unroll
    for (int ks = 0; ks < 6; ks++) {
      unsigned short* wb = lds + ((ks & 1) ? OFF_W1 : OFF_W0);
      // store W chunk ks (vmcnt wait for wv lands here)
#pragma unroll
      for (int i = 0; i < 3; i++) {
        int id = t + i * 512;
        *(short8*)(&wb[(id >> 3) * WPAD + (id & 7) * 8]) = wv[i];
      }
      // convert this chunk's x to bf16 A-frags
      short8 af[2][2];
#pragma unroll
      for (int mi = 0; mi < 2; mi++)
#pragma unroll
        for (int kk = 0; kk < 2; kk++)
#pragma unroll
          for (int h = 0; h < 2; h++)
#pragma unroll
            for (int j = 0; j < 4; j++)
              af[mi][kk][h * 4 + j] = (short)f2bf(nx[mi][kk][h][j]);
      // issue chunk ks+1 loads; in flight across barrier + MFMAs
      if (ks < 5) {
#pragma unroll
        for (int mi = 0; mi < 2; mi++)
#pragma unroll
          for (int kk = 0; kk < 2; kk++)
#pragma unroll
            for (int h = 0; h < 2; h++)
              nx[mi][kk][h] = *(const float4_*)(xw + mi * 16 * Cc + (ks + 1) * 64 + kk * 32 + h * 4);
#pragma unroll
        for (int i = 0; i < 3; i++) {
          int id = t + i * 512;
          wv[i] = *(const short8*)(wt + (size_t)(ks + 1) * WCH + (id >> 3) * 64 + (id & 7) * 8);
        }
      }
      // ONE barrier per chunk: lgkm drained; vm loads stay in flight
      asm volatile("s_waitcnt lgkmcnt(0)" ::: "memory");
      __builtin_amdgcn_s_barrier();
      __builtin_amdgcn_sched_barrier(0);
#pragma unroll
      for (int kk = 0; kk < 2; kk++) {
#pragma unroll
        for (int ni = 0; ni < 12; ni++) {
          short8 bf = *(const short8*)(&wb[(ni * 16 + fr) * WPAD + kk * 32 + fg * 8]);
          acc[0][ni] = __builtin_amdgcn_mfma_f32_16x16x32_bf16(af[0][kk], bf, acc[0][ni], 0, 0, 0);
          acc[1][ni] = __builtin_amdgcn_mfma_f32_16x16x32_bf16(af[1][kk], bf, acc[1][ni], 0, 0, 0);
        }
      }
    }
    __syncthreads();   // end phase A: all W-buffer reads done before aliased scatter

    // ================= phase B: scatter Q/K/V =================
#pragma unroll
    for (int mi = 0; mi < 2; mi++) {
      int row0 = wid * 32 + mi * 16 + fg * 4;
#pragma unroll
      for (int ni = 0; ni < 12; ni++) {
        int col = ni * 16 + fr;
        if (ni >= 8) {                      // V -> V^T [h][seq]
          short4_ pk;
#pragma unroll
          for (int r = 0; r < 4; r++) pk[r] = (short)f2bf(acc[mi][ni][r]);
          *(short4_*)(&vt_lds[(col - 128) * VTP + row0]) = pk;
        } else if (ni < 4) {                // Q -> [seq][h]
#pragma unroll
          for (int r = 0; r < 4; r++)
            q_lds[(row0 + r) * QBP + col] = f2bf(acc[mi][ni][r]);
        } else {                            // K -> [seq][h]
#pragma unroll
          for (int r = 0; r < 4; r++)
            k_lds[(row0 + r) * KP + (col - 64)] = f2bf(acc[mi][ni][r]);
        }
      }
    }
    __syncthreads();

    // cross-batch prefetch: issue batch bi+1's x-chunk-0 loads NOW; they
    // stream from HBM during phase C (~7 us), hiding their BW time + latency.
    if (bi == 0) {
      const float* xw2 = x + ((size_t)(b + 1) * Tt + wid * 32 + fr) * Cc + fg * 8;
#pragma unroll
      for (int mi = 0; mi < 2; mi++)
#pragma unroll
        for (int kk = 0; kk < 2; kk++)
#pragma unroll
          for (int h = 0; h < 2; h++)
            nx[mi][kk][h] = *(const float4_*)(xw2 + mi * 16 * Cc + kk * 32 + h * 4);
    }

    // ================= phase C: causal flash attn, swapped operands =================
    unsigned short* pw = lds + OFF_P + wid * 16 * PST;

    auto run_tile = [&](int qt) {
      short8 aq0 = *(const short8*)(&q_lds[(qt * 16 + fr) * QBP + fg * 8]);
      short8 aq1 = *(const short8*)(&q_lds[(qt * 16 + fr) * QBP + 32 + fg * 8]);
      float4_ o[4] = {(float4_)0.f, (float4_)0.f, (float4_)0.f, (float4_)0.f};
      float m = -3.0e38f, l = 0.f;
      const int qg = qt * 16 + fr;
      const int ktmax = qt >> 1;
      short8 kf0 = *(const short8*)(&k_lds[fr * KP + fg * 8]);
      short8 kf1 = *(const short8*)(&k_lds[(16 + fr) * KP + fg * 8]);
      short8 kf2 = *(const short8*)(&k_lds[fr * KP + 32 + fg * 8]);
      short8 kf3 = *(const short8*)(&k_lds[(16 + fr) * KP + 32 + fg * 8]);
      short8 bv0 = *(const short8*)(&vt_lds[fr * VTP + fg * 8]);
      short8 bv1 = *(const short8*)(&vt_lds[(16 + fr) * VTP + fg * 8]);
      short8 bv2 = *(const short8*)(&vt_lds[(32 + fr) * VTP + fg * 8]);
      short8 bv3 = *(const short8*)(&vt_lds[(48 + fr) * VTP + fg * 8]);
      for (int kt = 0; kt <= ktmax; kt++) {
        float4_ s0 = (float4_)0.f, s1 = (float4_)0.f;
        s0 = __builtin_amdgcn_mfma_f32_16x16x32_bf16(kf0, aq0, s0, 0, 0, 0);
        s1 = __builtin_amdgcn_mfma_f32_16x16x32_bf16(kf1, aq0, s1, 0, 0, 0);
        s0 = __builtin_amdgcn_mfma_f32_16x16x32_bf16(kf2, aq1, s0, 0, 0, 0);
        s1 = __builtin_amdgcn_mfma_f32_16x16x32_bf16(kf3, aq1, s1, 0, 0, 0);
        if (kt < ktmax) {
          int kb = (kt + 1) * 32;
          kf0 = *(const short8*)(&k_lds[(kb + fr) * KP + fg * 8]);
          kf1 = *(const short8*)(&k_lds[(kb + 16 + fr) * KP + fg * 8]);
          kf2 = *(const short8*)(&k_lds[(kb + fr) * KP + 32 + fg * 8]);
          kf3 = *(const short8*)(&k_lds[(kb + 16 + fr) * KP + 32 + fg * 8]);
        }
        bool edge = (kt == ktmax);
        float vs[8];
#pragma unroll
        for (int r = 0; r < 4; r++) {
          int kg0 = kt * 32 + fg * 4 + r;
          float a0 = s0[r] * SC, a1 = s1[r] * SC;
          if (edge && kg0 > qg)      a0 = -3.0e38f;
          if (edge && kg0 + 16 > qg) a1 = -3.0e38f;
          vs[r] = a0; vs[4 + r] = a1;
        }
        float mx = fmaxf(fmaxf(fmaxf(vs[0], vs[1]), fmaxf(vs[2], vs[3])),
                         fmaxf(fmaxf(vs[4], vs[5]), fmaxf(vs[6], vs[7])));
        mx = fmaxf(mx, __shfl_xor(mx, 16));
        mx = fmaxf(mx, __shfl_xor(mx, 32));
        if (!__all(mx - m <= 8.0f)) {   // defer-rescale (T13, THR=8)
          float mn = fmaxf(m, mx);
          float scal = exp2f((m - mn) * L2E);
          l *= scal;
#pragma unroll
          for (int nt = 0; nt < 4; nt++) o[nt] *= scal;
          m = mn;
        }
        float p[8]; float ps = 0.f;
#pragma unroll
        for (int j = 0; j < 8; j++) { p[j] = exp2f((vs[j] - m) * L2E); ps += p[j]; }
        ps += __shfl_xor(ps, 16);
        ps += __shfl_xor(ps, 32);
        l += ps;

        short4_ pk0, pk1;
#pragma unroll
        for (int r = 0; r < 4; r++) { pk0[r] = (short)f2bf(p[r]); pk1[r] = (short)f2bf(p[4 + r]); }
        *(short4_*)(&pw[fr * PST + fg * 4]) = pk0;
        *(short4_*)(&pw[fr * PST + 16 + fg * 4]) = pk1;
        asm volatile("s_waitcnt lgkmcnt(0)" ::: "memory");
        __builtin_amdgcn_sched_barrier(0);
        short8 pb = *(const short8*)(&pw[fr * PST + fg * 8]);
        o[0] = __builtin_amdgcn_mfma_f32_16x16x32_bf16(bv0, pb, o[0], 0, 0, 0);
        o[1] = __builtin_amdgcn_mfma_f32_16x16x32_bf16(bv1, pb, o[1], 0, 0, 0);
        o[2] = __builtin_amdgcn_mfma_f32_16x16x32_bf16(bv2, pb, o[2], 0, 0, 0);
        o[3] = __builtin_amdgcn_mfma_f32_16x16x32_bf16(bv3, pb, o[3], 0, 0, 0);
        if (kt < ktmax) {
          int kb = (kt + 1) * 32;
          bv0 = *(const short8*)(&vt_lds[fr * VTP + kb + fg * 8]);
          bv1 = *(const short8*)(&vt_lds[(16 + fr) * VTP + kb + fg * 8]);
          bv2 = *(const short8*)(&vt_lds[(32 + fr) * VTP + kb + fg * 8]);
          bv3 = *(const short8*)(&vt_lds[(48 + fr) * VTP + kb + fg * 8]);
        }
      }
      float inv = 1.f / l;
#pragma unroll
      for (int nt = 0; nt < 4; nt++) {
        float4_ ov = o[nt] * inv;
        *(float4_*)(&out[((size_t)b * Tt + qt * 16 + fr) * Hh + nt * 16 + fg * 4]) = ov;
      }
    };
    run_tile(wid);        // balanced causal split: 9 kt-steps per wave
    run_tile(15 - wid);

    if (bi == 0) __syncthreads();   // C LDS reads done before batch 1's A stores
  }
}

extern "C" void kernel_launch(void* const* d_in, const int* in_sizes, int n_in,
                              void* d_out, int out_size, void* d_ws, size_t ws_size,
                              hipStream_t stream) {
  const float* x  = (const float*)d_in[0];
  const float* wq = (const float*)d_in[1];
  const float* wk = (const float*)d_in[2];
  const float* wv = (const float*)d_in[3];
  unsigned short* wt = (unsigned short*)d_ws;   // 6 chunks x 192*64 bf16
  float* out = (float*)d_out;

  hipLaunchKernelGGL(wtrans_kernel, dim3(24),  dim3(256), 0, stream, wq, wk, wv, wt);
  hipLaunchKernelGGL(fused_kernel,  dim3(256), dim3(512), 0, stream, x, wt, out);
}

// Round 15
// 63.027 us; speedup vs baseline: 1.3184x; 1.3184x over previous
//
#include <hip/hip_runtime.h>
#include <hip/hip_bf16.h>
#include <math.h>

#define Bb 512
#define Tt 256
#define Cc 384
#define Hh 64

#define PST  40    // P tile stride (shorts) — unchanged
#define WCH  12288 // chunk-major W: 192*64 shorts per k-chunk

// LDS (shorts), all natural strides + XOR swizzle (no pads):
//   K  [256][64]  Q [256][64]  VT [64][256]  P 8*16*PST
// Phase-A W double buffer (2 x [192][64]) aliases the K+VT front.
#define OFF_K  0
#define OFF_VT 16384
#define OFF_Q  32768
#define OFF_P  49152
#define LDST   54272               // shorts = 108,544 B -> 1 block/CU
#define OFF_W0 0
#define OFF_W1 12288               // ends 24576 <= 32768 (inside K+VT)

typedef __attribute__((ext_vector_type(8))) short short8;
typedef __attribute__((ext_vector_type(4))) short short4_;
typedef __attribute__((ext_vector_type(4))) float float4_;

static __device__ __forceinline__ unsigned short f2bf(float f) {
  __hip_bfloat16 h = __float2bfloat16(f);
  return *reinterpret_cast<unsigned short*>(&h);
}

// T2-style XOR swizzle: 8-short (16B) slots, slot ^= row&7.
// [*][64]-short regions (K, Q, W bufs):
static __device__ __forceinline__ int swz64(int row, int col) {
  return row * 64 + ((((col >> 3) ^ (row & 7)) << 3) | (col & 7));
}
// [64][256]-short region (V^T): swizzle low 3 bits of the 16B-slot index:
static __device__ __forceinline__ int swz256(int row, int col) {
  int c8 = col >> 3;
  return row * 256 + ((((c8 & ~7) | ((c8 & 7) ^ (row & 7))) << 3) | (col & 7));
}

// ---------------- kernel 0: pack W chunk-major bf16: wt[ks][192][64] ----------------
__global__ __launch_bounds__(256) void wtrans_kernel(
    const float* __restrict__ wq, const float* __restrict__ wk,
    const float* __restrict__ wv, unsigned short* __restrict__ wt) {
  __shared__ float tl[384 * 8];
  const int blk = blockIdx.x;
  const int wsel = blk >> 3, n0 = (blk & 7) * 8;
  const float* w = (wsel == 0) ? wq : (wsel == 1) ? wk : wv;
  const int t = threadIdx.x;
#pragma unroll
  for (int i = 0; i < 3; i++) {
    int id = i * 256 + t;
    int row = id >> 1, sg = id & 1;
    float4_ v = *(const float4_*)(w + row * Hh + n0 + sg * 4);
    *(float4_*)(&tl[row * 8 + sg * 4]) = v;
  }
  __syncthreads();
#pragma unroll
  for (int i = 0; i < 12; i++) {
    int id = i * 256 + t;
    int n = id / 384, k = id % 384;
    int row = wsel * 64 + n0 + n;
    wt[(size_t)(k >> 6) * WCH + row * 64 + (k & 63)] = f2bf(tl[k * 8 + n]);
  }
}

// ---------------- fused kernel: per-batch QKV proj + causal flash attn ----------------
// R12 structure verbatim; only change: XOR-swizzled LDS addressing for the
// four row-strided regions. Rationale: every b128 fragment read here has
// fr-varying rows at 16B-aligned stride -> at most 8 distinct banks -> 8-way
// conflict (R14: 4.18M conflict cycles). Swizzle spreads to <=2/bank.
__global__ __launch_bounds__(512, 1) void fused_kernel(
    const float* __restrict__ x, const unsigned short* __restrict__ wt,
    float* __restrict__ out) {
  __shared__ unsigned short lds[LDST];
  unsigned short* k_lds  = lds + OFF_K;
  unsigned short* vt_lds = lds + OFF_VT;
  unsigned short* q_lds  = lds + OFF_Q;

  const int t = threadIdx.x;
  const int wid = t >> 6, lane = t & 63;
  const int fr = lane & 15, fg = lane >> 4;
  const int b = blockIdx.x;
  const float* xb = x + (size_t)b * Tt * Cc;
  const float* xw = xb + (size_t)(wid * 32 + fr) * Cc + fg * 8;

  // ================= phase A: QKV = x[b] @ W  (M=256, N=192, K=384) =================
  float4_ acc[2][12];
#pragma unroll
  for (int i = 0; i < 2; i++)
#pragma unroll
    for (int j = 0; j < 12; j++) acc[i][j] = (float4_)0.f;

  float4_ nx[2][2][2];
#pragma unroll
  for (int mi = 0; mi < 2; mi++)
#pragma unroll
    for (int kk = 0; kk < 2; kk++)
#pragma unroll
      for (int h = 0; h < 2; h++)
        nx[mi][kk][h] = *(const float4_*)(xw + mi * 16 * Cc + kk * 32 + h * 4);

  short8 wv[3];
#pragma unroll
  for (int i = 0; i < 3; i++) {
    int id = t + i * 512;
    wv[i] = *(const short8*)(wt + (id >> 3) * 64 + (id & 7) * 8);
  }

#pragma unroll
  for (int ks = 0; ks < 6; ks++) {
    unsigned short* wb = lds + ((ks & 1) ? OFF_W1 : OFF_W0);
    // store W chunk ks, swizzled (vmcnt wait for wv lands here)
#pragma unroll
    for (int i = 0; i < 3; i++) {
      int id = t + i * 512;
      *(short8*)(&wb[swz64(id >> 3, (id & 7) * 8)]) = wv[i];
    }
    // convert this chunk's x to bf16 A-frags
    short8 af[2][2];
#pragma unroll
    for (int mi = 0; mi < 2; mi++)
#pragma unroll
      for (int kk = 0; kk < 2; kk++)
#pragma unroll
        for (int h = 0; h < 2; h++)
#pragma unroll
          for (int j = 0; j < 4; j++)
            af[mi][kk][h * 4 + j] = (short)f2bf(nx[mi][kk][h][j]);
    // issue chunk ks+1 loads; in flight across barrier + MFMAs
    if (ks < 5) {
#pragma unroll
      for (int mi = 0; mi < 2; mi++)
#pragma unroll
        for (int kk = 0; kk < 2; kk++)
#pragma unroll
          for (int h = 0; h < 2; h++)
            nx[mi][kk][h] = *(const float4_*)(xw + mi * 16 * Cc + (ks + 1) * 64 + kk * 32 + h * 4);
#pragma unroll
      for (int i = 0; i < 3; i++) {
        int id = t + i * 512;
        wv[i] = *(const short8*)(wt + (size_t)(ks + 1) * WCH + (id >> 3) * 64 + (id & 7) * 8);
      }
    }
    // ONE barrier per chunk: lgkm drained; vm loads stay in flight
    asm volatile("s_waitcnt lgkmcnt(0)" ::: "memory");
    __builtin_amdgcn_s_barrier();
    __builtin_amdgcn_sched_barrier(0);
#pragma unroll
    for (int kk = 0; kk < 2; kk++) {
#pragma unroll
      for (int ni = 0; ni < 12; ni++) {
        short8 bf = *(const short8*)(&wb[swz64(ni * 16 + fr, kk * 32 + fg * 8)]);
        acc[0][ni] = __builtin_amdgcn_mfma_f32_16x16x32_bf16(af[0][kk], bf, acc[0][ni], 0, 0, 0);
        acc[1][ni] = __builtin_amdgcn_mfma_f32_16x16x32_bf16(af[1][kk], bf, acc[1][ni], 0, 0, 0);
      }
    }
  }
  __syncthreads();   // end phase A: all W-buffer reads done before aliased scatter

  // ================= phase B: scatter Q/K/V (swizzled writes) =================
  // acc D-layout: row = wid*32 + mi*16 + fg*4 + r, col = ni*16 + fr
#pragma unroll
  for (int mi = 0; mi < 2; mi++) {
    int row0 = wid * 32 + mi * 16 + fg * 4;
#pragma unroll
    for (int ni = 0; ni < 12; ni++) {
      int col = ni * 16 + fr;
      if (ni >= 8) {                      // V -> V^T [h][seq]
        short4_ pk;
#pragma unroll
        for (int r = 0; r < 4; r++) pk[r] = (short)f2bf(acc[mi][ni][r]);
        *(short4_*)(&vt_lds[swz256(col - 128, row0)]) = pk;
      } else if (ni < 4) {                // Q -> [seq][h]
#pragma unroll
        for (int r = 0; r < 4; r++)
          q_lds[swz64(row0 + r, col)] = f2bf(acc[mi][ni][r]);
      } else {                            // K -> [seq][h]
#pragma unroll
        for (int r = 0; r < 4; r++)
          k_lds[swz64(row0 + r, col - 64)] = f2bf(acc[mi][ni][r]);
      }
    }
  }
  __syncthreads();

  // ================= phase C: causal flash attn, swapped-operand layout =================
  unsigned short* pw = lds + OFF_P + wid * 16 * PST;   // wave-private [16 q][32 k]
  const float SC  = 0.05103103630798288f;              // 384^-0.5
  const float L2E = 1.4426950408889634f;

  auto run_tile = [&](int qt) {
    short8 aq0 = *(const short8*)(&q_lds[swz64(qt * 16 + fr, fg * 8)]);
    short8 aq1 = *(const short8*)(&q_lds[swz64(qt * 16 + fr, 32 + fg * 8)]);
    float4_ o[4] = {(float4_)0.f, (float4_)0.f, (float4_)0.f, (float4_)0.f};
    float m = -3.0e38f, l = 0.f;
    const int qg = qt * 16 + fr;
    const int ktmax = qt >> 1;
    short8 kf0 = *(const short8*)(&k_lds[swz64(fr, fg * 8)]);
    short8 kf1 = *(const short8*)(&k_lds[swz64(16 + fr, fg * 8)]);
    short8 kf2 = *(const short8*)(&k_lds[swz64(fr, 32 + fg * 8)]);
    short8 kf3 = *(const short8*)(&k_lds[swz64(16 + fr, 32 + fg * 8)]);
    short8 bv0 = *(const short8*)(&vt_lds[swz256(fr, fg * 8)]);
    short8 bv1 = *(const short8*)(&vt_lds[swz256(16 + fr, fg * 8)]);
    short8 bv2 = *(const short8*)(&vt_lds[swz256(32 + fr, fg * 8)]);
    short8 bv3 = *(const short8*)(&vt_lds[swz256(48 + fr, fg * 8)]);
    for (int kt = 0; kt <= ktmax; kt++) {
      float4_ s0 = (float4_)0.f, s1 = (float4_)0.f;
      s0 = __builtin_amdgcn_mfma_f32_16x16x32_bf16(kf0, aq0, s0, 0, 0, 0);
      s1 = __builtin_amdgcn_mfma_f32_16x16x32_bf16(kf1, aq0, s1, 0, 0, 0);
      s0 = __builtin_amdgcn_mfma_f32_16x16x32_bf16(kf2, aq1, s0, 0, 0, 0);
      s1 = __builtin_amdgcn_mfma_f32_16x16x32_bf16(kf3, aq1, s1, 0, 0, 0);
      if (kt < ktmax) {
        int kb = (kt + 1) * 32;
        kf0 = *(const short8*)(&k_lds[swz64(kb + fr, fg * 8)]);
        kf1 = *(const short8*)(&k_lds[swz64(kb + 16 + fr, fg * 8)]);
        kf2 = *(const short8*)(&k_lds[swz64(kb + fr, 32 + fg * 8)]);
        kf3 = *(const short8*)(&k_lds[swz64(kb + 16 + fr, 32 + fg * 8)]);
      }
      bool edge = (kt == ktmax);
      float vs[8];
#pragma unroll
      for (int r = 0; r < 4; r++) {
        int kg0 = kt * 32 + fg * 4 + r;
        float a0 = s0[r] * SC, a1 = s1[r] * SC;
        if (edge && kg0 > qg)      a0 = -3.0e38f;
        if (edge && kg0 + 16 > qg) a1 = -3.0e38f;
        vs[r] = a0; vs[4 + r] = a1;
      }
      float mx = fmaxf(fmaxf(fmaxf(vs[0], vs[1]), fmaxf(vs[2], vs[3])),
                       fmaxf(fmaxf(vs[4], vs[5]), fmaxf(vs[6], vs[7])));
      mx = fmaxf(mx, __shfl_xor(mx, 16));
      mx = fmaxf(mx, __shfl_xor(mx, 32));
      if (!__all(mx - m <= 8.0f)) {   // defer-rescale (T13, THR=8)
        float mn = fmaxf(m, mx);
        float scal = exp2f((m - mn) * L2E);
        l *= scal;
#pragma unroll
        for (int nt = 0; nt < 4; nt++) o[nt] *= scal;
        m = mn;
      }
      float p[8]; float ps = 0.f;
#pragma unroll
      for (int j = 0; j < 8; j++) { p[j] = exp2f((vs[j] - m) * L2E); ps += p[j]; }
      ps += __shfl_xor(ps, 16);
      ps += __shfl_xor(ps, 32);
      l += ps;

      short4_ pk0, pk1;
#pragma unroll
      for (int r = 0; r < 4; r++) { pk0[r] = (short)f2bf(p[r]); pk1[r] = (short)f2bf(p[4 + r]); }
      *(short4_*)(&pw[fr * PST + fg * 4]) = pk0;
      *(short4_*)(&pw[fr * PST + 16 + fg * 4]) = pk1;
      asm volatile("s_waitcnt lgkmcnt(0)" ::: "memory");
      __builtin_amdgcn_sched_barrier(0);
      short8 pb = *(const short8*)(&pw[fr * PST + fg * 8]);
      o[0] = __builtin_amdgcn_mfma_f32_16x16x32_bf16(bv0, pb, o[0], 0, 0, 0);
      o[1] = __builtin_amdgcn_mfma_f32_16x16x32_bf16(bv1, pb, o[1], 0, 0, 0);
      o[2] = __builtin_amdgcn_mfma_f32_16x16x32_bf16(bv2, pb, o[2], 0, 0, 0);
      o[3] = __builtin_amdgcn_mfma_f32_16x16x32_bf16(bv3, pb, o[3], 0, 0, 0);
      if (kt < ktmax) {
        int kb = (kt + 1) * 32;
        bv0 = *(const short8*)(&vt_lds[swz256(fr, kb + fg * 8)]);
        bv1 = *(const short8*)(&vt_lds[swz256(16 + fr, kb + fg * 8)]);
        bv2 = *(const short8*)(&vt_lds[swz256(32 + fr, kb + fg * 8)]);
        bv3 = *(const short8*)(&vt_lds[swz256(48 + fr, kb + fg * 8)]);
      }
    }
    float inv = 1.f / l;
#pragma unroll
    for (int nt = 0; nt < 4; nt++) {
      float4_ ov = o[nt] * inv;
      *(float4_*)(&out[((size_t)b * Tt + qt * 16 + fr) * Hh + nt * 16 + fg * 4]) = ov;
    }
  };
  run_tile(wid);        // balanced causal split: 9 kt-steps per wave
  run_tile(15 - wid);
}

extern "C" void kernel_launch(void* const* d_in, const int* in_sizes, int n_in,
                              void* d_out, int out_size, void* d_ws, size_t ws_size,
                              hipStream_t stream) {
  const float* x  = (const float*)d_in[0];
  const float* wq = (const float*)d_in[1];
  const float* wk = (const float*)d_in[2];
  const float* wv = (const float*)d_in[3];
  unsigned short* wt = (unsigned short*)d_ws;   // 6 chunks x 192*64 bf16
  float* out = (float*)d_out;

  hipLaunchKernelGGL(wtrans_kernel, dim3(24), dim3(256), 0, stream, wq, wk, wv, wt);
  hipLaunchKernelGGL(fused_kernel,  dim3(Bb), dim3(512), 0, stream, x, wt, out);
}